// Round 8
// baseline (97.149 us; speedup 1.0000x reference)
//
#include <hip/hip_runtime.h>
#include <hip/hip_fp16.h>
#include <hip/hip_cooperative_groups.h>

namespace cg = cooperative_groups;

#define BATCH 2
#define CCH   256
#define WDIM  64
#define HW    4096   // 64*64
#define KWIN  49

// corr tile geometry: 8 wide (x) x 4 tall (y) = 32 pixels per block
#define UW    15     // union window cols  (8 px x-span + 7)
#define UH    11     // union window rows  (4 px y-span + 7)
#define UPOS  165    // UW*UH
#define DSTR  177    // D row stride (odd -> bank spread)
#define BITEMS (UPOS * 16)   // 2640 uint4 items per B half
#define NSLOT 6              // ceil(2640 / 512)

using f16x8 = __attribute__((ext_vector_type(8))) _Float16;
using f32x4 = __attribute__((ext_vector_type(4))) float;

__device__ __forceinline__ __half2 u2h2(unsigned u) {
    union { unsigned u; __half2 h; } v; v.u = u; return v.h;
}
__device__ __forceinline__ unsigned h22u(__half2 h) {
    union { unsigned u; __half2 h; } v; v.h = h; return v.u;
}
__device__ __forceinline__ f16x8 ldfrag(const ushort* p) {
    return __builtin_bit_cast(f16x8, *(const uint4*)p);
}

// ---------------------------------------------------------------------------
// Cooperative megakernel: T (transpose) -> grid.sync -> W (warp) -> grid.sync
// -> C (MFMA corr). Grid 256 blocks x 512 threads, co-resident (62 KB LDS,
// 1-2 blocks/CU). Eliminates 2 of 3 dispatches.
// ---------------------------------------------------------------------------
__global__ __launch_bounds__(512) void mega_kernel(
    const float* __restrict__ f1, const float* __restrict__ f2,
    const float* __restrict__ c1, const float* __restrict__ c0,
    __half* __restrict__ f1t, __half* __restrict__ f2t,
    __half* __restrict__ f2wt, float* __restrict__ out)
{
    __shared__ __align__(16) char RAW[16384 + 176 * 128 * 2];
    __shared__ float s_fx[32], s_fy[32];
    __shared__ int   s_lbx[32], s_lby[32];

    cg::grid_group grid = cg::this_grid();
    const int t   = threadIdx.x;
    const int bid = blockIdx.x;
    float* outc = out + BATCH * 2 * HW;

    // ================= Phase T: transpose f1,f2 -> channel-last f16 ========
    {
        const int b   = bid >> 7;                // 128 blocks per batch
        const int r   = bid & 127;
        const int nb  = (r & 63) << 6;           // 64-pixel group
        const int ch0 = (r >> 6) << 7;           // 0 or 128

        // c1 passthrough (out 0): 256 blocks x 64 = 16384 floats
        if (t < 64) {
            const int idx = bid * 64 + t;
            out[idx] = c1[idx];
        }

        float* s1 = (float*)RAW;                 // [32][65]
        float* s2 = (float*)RAW + 32 * 65;       // [32][65]

        const int pix = t & 63;
        const int tq  = t >> 6;                  // wave 0..7
        const int n   = nb + pix;
        const int lo  = t & 7;                   // channel quad 0..7
        const int pq  = t >> 3;                  // pixel 0..63
        const int c4  = 4 * lo;

        #pragma unroll
        for (int s = 0; s < 4; ++s) {
            const int cc = ch0 + s * 32;
            const float* f1b = f1 + ((size_t)b * CCH + cc) * HW;
            const float* f2b = f2 + ((size_t)b * CCH + cc) * HW;
            #pragma unroll
            for (int jj = 0; jj < 4; ++jj) {
                const int cl = tq * 4 + jj;      // local channel 0..31
                s1[cl * 65 + pix] = f1b[(size_t)cl * HW + n];
                s2[cl * 65 + pix] = f2b[(size_t)cl * HW + n];
            }
            __syncthreads();
            const size_t base = ((size_t)(b * HW + nb + pq)) * CCH + cc + c4;
            uint2 va, vb;
            va.x = h22u(__float22half2_rn(make_float2(s1[(c4 + 0) * 65 + pq], s1[(c4 + 1) * 65 + pq])));
            va.y = h22u(__float22half2_rn(make_float2(s1[(c4 + 2) * 65 + pq], s1[(c4 + 3) * 65 + pq])));
            vb.x = h22u(__float22half2_rn(make_float2(s2[(c4 + 0) * 65 + pq], s2[(c4 + 1) * 65 + pq])));
            vb.y = h22u(__float22half2_rn(make_float2(s2[(c4 + 2) * 65 + pq], s2[(c4 + 3) * 65 + pq])));
            *(uint2*)((ushort*)f1t + base) = va;
            *(uint2*)((ushort*)f2t + base) = vb;
            __syncthreads();
        }
    }

    grid.sync();   // f1t, f2t complete

    // ================= Phase W: bilinear warp in channel-last space ========
    {
        const int chunk = t & 31;     // uint4 chunk within 256 ch
        const int pl    = t >> 5;     // 0..15
        #pragma unroll
        for (int p = 0; p < 2; ++p) {
            const int ng = bid * 32 + p * 16 + pl;
            const int b  = ng >> 12;
            const int n  = ng & 4095;

            const float cx = c1[(b * 2 + 0) * HW + n];
            const float cy = c1[(b * 2 + 1) * HW + n];
            const float x0f = floorf(cx), y0f = floorf(cy);
            const float fx = cx - x0f, fy = cy - y0f;
            const int ix0 = (int)x0f, iy0 = (int)y0f;
            const int ix1 = ix0 + 1,  iy1 = iy0 + 1;

            float w00 = (1.f - fx) * (1.f - fy);
            float w01 = fx * (1.f - fy);
            float w10 = (1.f - fx) * fy;
            float w11 = fx * fy;
            if (ix0 < 0 || ix0 >= WDIM) { w00 = 0.f; w10 = 0.f; }
            if (ix1 < 0 || ix1 >= WDIM) { w01 = 0.f; w11 = 0.f; }
            if (iy0 < 0 || iy0 >= WDIM) { w00 = 0.f; w01 = 0.f; }
            if (iy1 < 0 || iy1 >= WDIM) { w10 = 0.f; w11 = 0.f; }
            const int xc0 = min(max(ix0, 0), WDIM - 1);
            const int xc1 = min(max(ix1, 0), WDIM - 1);
            const int yc0 = min(max(iy0, 0), WDIM - 1);
            const int yc1 = min(max(iy1, 0), WDIM - 1);

            const ushort* base = (const ushort*)f2t + ((size_t)b * HW) * CCH + chunk * 8;
            const uint4 v00 = *(const uint4*)(base + (size_t)(yc0 * WDIM + xc0) * CCH);
            const uint4 v01 = *(const uint4*)(base + (size_t)(yc0 * WDIM + xc1) * CCH);
            const uint4 v10 = *(const uint4*)(base + (size_t)(yc1 * WDIM + xc0) * CCH);
            const uint4 v11 = *(const uint4*)(base + (size_t)(yc1 * WDIM + xc1) * CCH);

            float acc[8] = {0.f, 0.f, 0.f, 0.f, 0.f, 0.f, 0.f, 0.f};
            auto addc = [&](uint4 u, float w) {
                float2 m;
                m = __half22float2(u2h2(u.x)); acc[0] += w * m.x; acc[1] += w * m.y;
                m = __half22float2(u2h2(u.y)); acc[2] += w * m.x; acc[3] += w * m.y;
                m = __half22float2(u2h2(u.z)); acc[4] += w * m.x; acc[5] += w * m.y;
                m = __half22float2(u2h2(u.w)); acc[6] += w * m.x; acc[7] += w * m.y;
            };
            addc(v00, w00); addc(v01, w01); addc(v10, w10); addc(v11, w11);

            uint4 o;
            o.x = h22u(__float22half2_rn(make_float2(acc[0], acc[1])));
            o.y = h22u(__float22half2_rn(make_float2(acc[2], acc[3])));
            o.z = h22u(__float22half2_rn(make_float2(acc[4], acc[5])));
            o.w = h22u(__float22half2_rn(make_float2(acc[6], acc[7])));
            *(uint4*)((ushort*)f2wt + ((size_t)(b * HW + n)) * CCH + chunk * 8) = o;
        }
    }

    grid.sync();   // f2wt complete

    // ================= Phase C: tiled MFMA correlation ====================
    {
        ushort* A16 = (ushort*)RAW;
        ushort* B16 = (ushort*)(RAW + 16384);
        float*  Dex = (float*)(RAW + 16384);      // overlays B after compute

        const int l  = t & 63;
        const int wv = t >> 6;

        // XCD-aware bijective swizzle: 256 = 8 * 32
        const int swz = (bid & 7) * 32 + (bid >> 3);
        const int b   = swz >> 7;
        const int tau = swz & 127;
        const int ty  = tau >> 3, tx = tau & 7;
        const int n0  = ty * 256 + tx * 8;        // tile base pixel

        const ushort* f1u = (const ushort*)f1t + ((size_t)b * HW) * CCH;
        const ushort* f2u = (const ushort*)f2wt + ((size_t)b * HW) * CCH;

        // ---- issue A loads first ----
        const int r0 = t >> 5,         c0i = t & 31;
        const int r1 = (t + 512) >> 5, c1i = (t + 512) & 31;
        const int an0 = n0 + ((r0 >> 3) << 6) + (r0 & 7);
        const int an1 = n0 + ((r1 >> 3) << 6) + (r1 & 7);
        const uint4 av0 = *(const uint4*)(f1u + (size_t)an0 * CCH + c0i * 8);
        const uint4 av1 = *(const uint4*)(f1u + (size_t)an1 * CCH + c1i * 8);

        // ---- meta: every wave computes the span reduce redundantly ----
        float pcx = 0.f, pcy = 0.f;
        int ifx = 0, ify = 0;
        if (l < 32) {
            const int n = n0 + ((l >> 3) << 6) + (l & 7);
            pcx = c0[(b * 2 + 0) * HW + n];
            pcy = c0[(b * 2 + 1) * HW + n];
            ifx = (int)floorf(pcx);
            ify = (int)floorf(pcy);
        }
        int mnx = (l < 32) ? ifx : 0x7fffffff;
        int mxx = (l < 32) ? ifx : (-0x7fffffff - 1);
        int mny = (l < 32) ? ify : 0x7fffffff;
        int mxy = (l < 32) ? ify : (-0x7fffffff - 1);
        #pragma unroll
        for (int off = 1; off < 64; off <<= 1) {
            mnx = min(mnx, __shfl_xor(mnx, off, 64));
            mxx = max(mxx, __shfl_xor(mxx, off, 64));
            mny = min(mny, __shfl_xor(mny, off, 64));
            mxy = max(mxy, __shfl_xor(mxy, off, 64));
        }
        const int bx0 = mnx - 3, by0 = mny - 3;
        const int contained = (mxx - mnx <= 7) && (mxy - mny <= 3);

        if (wv == 0 && l < 32) {
            s_fx[l]  = pcx - floorf(pcx);
            s_fy[l]  = pcy - floorf(pcy);
            s_lbx[l] = ifx - mnx;
            s_lby[l] = ify - mny;
        }

        if (contained) {
            // ---- issue BOTH B-half loads into registers (T14 split) ----
            uint4 b0[NSLOT], b1[NSLOT];
            int   bofs[NSLOT];
            #pragma unroll
            for (int k = 0; k < NSLOT; ++k) {
                const int idx = t + k * 512;
                bofs[k] = -1;
                b0[k] = uint4{0u, 0u, 0u, 0u};
                b1[k] = uint4{0u, 0u, 0u, 0u};
                if (idx < BITEMS) {
                    const int r = idx >> 4, c = idx & 15;
                    const int wy = r / UW, wx = r - wy * UW;
                    const int py = by0 + wy, px = bx0 + wx;
                    bofs[k] = r * 128 + ((c ^ (r & 7)) << 3);
                    if (px >= 0 && px < WDIM && py >= 0 && py < WDIM) {
                        const ushort* src = f2u + (size_t)(py * WDIM + px) * CCH + c * 8;
                        b0[k] = *(const uint4*)(src);
                        b1[k] = *(const uint4*)(src + 128);
                    }
                }
            }

            // ---- ds_write A + B half 0 ----
            *(uint4*)(A16 + r0 * 256 + ((c0i ^ (r0 & 7)) << 3)) = av0;
            *(uint4*)(A16 + r1 * 256 + ((c1i ^ (r1 & 7)) << 3)) = av1;
            #pragma unroll
            for (int k = 0; k < NSLOT; ++k)
                if (bofs[k] >= 0) *(uint4*)(B16 + bofs[k]) = b0[k];
            __syncthreads();

            // ---- MFMA setup ----
            const int mt = wv & 1;          // m-tile (16 px)
            const int ng = wv >> 1;         // n-group
            const int nnt = (ng == 3) ? 2 : 3;
            int nt[3] = {ng, ng + 4, ng + 8};
            f32x4 acc[3];
            #pragma unroll
            for (int i = 0; i < 3; ++i) acc[i] = f32x4{0.f, 0.f, 0.f, 0.f};

            const int g    = l >> 4;
            const int arow = mt * 16 + (l & 15);
            const int axr  = arow & 7;

            // half 0
            {
                f16x8 af[4];
                #pragma unroll
                for (int s = 0; s < 4; ++s)
                    af[s] = ldfrag(A16 + arow * 256 + (((s * 4 + g) ^ axr) << 3));
                #pragma unroll
                for (int i = 0; i < 3; ++i) if (i < nnt) {
                    const int brow = nt[i] * 16 + (l & 15);
                    const int bxr  = brow & 7;
                    #pragma unroll
                    for (int s = 0; s < 4; ++s) {
                        const f16x8 bf = ldfrag(B16 + brow * 128 + (((s * 4 + g) ^ bxr) << 3));
                        acc[i] = __builtin_amdgcn_mfma_f32_16x16x32_f16(af[s], bf, acc[i], 0, 0, 0);
                    }
                }
            }
            __syncthreads();   // all B-half-0 reads done

            // ---- ds_write B half 1 (loads returned during half-0 MFMA) ----
            #pragma unroll
            for (int k = 0; k < NSLOT; ++k)
                if (bofs[k] >= 0) *(uint4*)(B16 + bofs[k]) = b1[k];
            __syncthreads();

            // half 1
            {
                f16x8 af[4];
                #pragma unroll
                for (int s = 0; s < 4; ++s)
                    af[s] = ldfrag(A16 + arow * 256 + (((16 + s * 4 + g) ^ axr) << 3));
                #pragma unroll
                for (int i = 0; i < 3; ++i) if (i < nnt) {
                    const int brow = nt[i] * 16 + (l & 15);
                    const int bxr  = brow & 7;
                    #pragma unroll
                    for (int s = 0; s < 4; ++s) {
                        const f16x8 bf = ldfrag(B16 + brow * 128 + (((s * 4 + g) ^ bxr) << 3));
                        acc[i] = __builtin_amdgcn_mfma_f32_16x16x32_f16(af[s], bf, acc[i], 0, 0, 0);
                    }
                }
            }
            __syncthreads();   // A,B dead -> D may overlay

            // ---- D -> LDS ----
            #pragma unroll
            for (int i = 0; i < 3; ++i) if (i < nnt) {
                #pragma unroll
                for (int r4 = 0; r4 < 4; ++r4) {
                    Dex[(mt * 16 + (l >> 4) * 4 + r4) * DSTR + nt[i] * 16 + (l & 15)] = acc[i][r4];
                }
            }
            __syncthreads();

            // ---- output: bilinear combine of 4 D entries per (pixel, k) ----
            for (int idx = t; idx < 32 * KWIN; idx += 512) {
                const int p = idx & 31, k = idx >> 5;
                const int dyi = k / 7, dxi = k - dyi * 7;
                const int pos = (s_lby[p] + dyi) * UW + s_lbx[p] + dxi;
                const float* dr = Dex + p * DSTR + pos;
                const float d00 = dr[0], d01 = dr[1], d10 = dr[UW], d11 = dr[UW + 1];
                const float fx = s_fx[p], fy = s_fy[p];
                const float w00 = (1.f - fx) * (1.f - fy);
                const float w01 = fx * (1.f - fy);
                const float w10 = (1.f - fx) * fy;
                const float w11 = fx * fy;
                const float r = (w00 * d00 + w01 * d01 + w10 * d10 + w11 * d11) * 0.0625f;
                const int n = n0 + ((p >> 3) << 6) + (p & 7);
                outc[(size_t)(b * KWIN + k) * HW + n] = r;
            }
        } else {
            // ---- fallback: general coords, per-pixel gather (block-uniform) ----
            float* sDw = (float*)RAW + wv * 64;
            for (int p = wv; p < 32; p += 8) {
                const int n = n0 + ((p >> 3) << 6) + (p & 7);
                const float cx = c0[(b * 2 + 0) * HW + n];
                const float cy = c0[(b * 2 + 1) * HW + n];
                const float x0f = floorf(cx), y0f = floorf(cy);
                const float fx = cx - x0f, fy = cy - y0f;
                const int bx = (int)x0f - 3, by = (int)y0f - 3;
                const int ix = l & 7, iy = l >> 3;
                const int px = bx + ix, py = by + iy;
                float a = 0.f;
                if (px >= 0 && px < WDIM && py >= 0 && py < WDIM) {
                    const ushort* qr = f1u + (size_t)n * CCH;
                    const ushort* wr = f2u + (size_t)(py * WDIM + px) * CCH;
                    for (int c = 0; c < 32; ++c) {
                        const uint4 uq = *(const uint4*)(qr + c * 8);
                        const uint4 uw = *(const uint4*)(wr + c * 8);
                        float2 m;
                        m = __half22float2(__hmul2(u2h2(uq.x), u2h2(uw.x))); a += m.x + m.y;
                        m = __half22float2(__hmul2(u2h2(uq.y), u2h2(uw.y))); a += m.x + m.y;
                        m = __half22float2(__hmul2(u2h2(uq.z), u2h2(uw.z))); a += m.x + m.y;
                        m = __half22float2(__hmul2(u2h2(uq.w), u2h2(uw.w))); a += m.x + m.y;
                    }
                }
                sDw[l] = a;   // same-wave producer/consumer
                const int k = l;
                if (k < KWIN) {
                    const int dyi = k / 7, dxi = k - dyi * 7;
                    const int s = dyi * 8 + dxi;
                    const float d00 = sDw[s], d01 = sDw[s + 1];
                    const float d10 = sDw[s + 8], d11 = sDw[s + 9];
                    const float w00 = (1.f - fx) * (1.f - fy);
                    const float w01 = fx * (1.f - fy);
                    const float w10 = (1.f - fx) * fy;
                    const float w11 = fx * fy;
                    const float r = (w00 * d00 + w01 * d01 + w10 * d10 + w11 * d11) * 0.0625f;
                    outc[(size_t)(b * KWIN + k) * HW + n] = r;
                }
            }
        }
    }
}

extern "C" void kernel_launch(void* const* d_in, const int* in_sizes, int n_in,
                              void* d_out, int out_size, void* d_ws, size_t ws_size,
                              hipStream_t stream) {
    (void)in_sizes; (void)n_in; (void)out_size; (void)ws_size;
    const float* f1 = (const float*)d_in[0];
    const float* f2 = (const float*)d_in[1];
    const float* c1 = (const float*)d_in[2];
    const float* c0 = (const float*)d_in[3];
    float* out = (float*)d_out;

    const size_t PLANE = (size_t)BATCH * HW * CCH;   // 2M halfs = 4 MB
    __half* f1t  = (__half*)d_ws;          // [B,HW,C] f16
    __half* f2wt = f1t + PLANE;            // warped  [B,HW,C] f16
    __half* f2t  = f2wt + PLANE;           // plain   [B,HW,C] f16

    void* args[] = {(void*)&f1, (void*)&f2, (void*)&c1, (void*)&c0,
                    (void*)&f1t, (void*)&f2t, (void*)&f2wt, (void*)&out};
    hipLaunchCooperativeKernel((const void*)mega_kernel, dim3(256), dim3(512),
                               args, 0, stream);
}

// Round 9
// 20.013 us; speedup vs baseline: 4.8543x; 4.8543x over previous
//
#include <hip/hip_runtime.h>
#include <hip/hip_fp16.h>

#define BATCH 2
#define CCH   256
#define WDIM  64
#define HW    4096   // 64*64
#define KWIN  49

// corr tile geometry: 8 wide (x) x 4 tall (y) = 32 pixels per block
#define UW    15     // union window cols  (8 px x-span + 7)
#define UH    11     // union window rows  (4 px y-span + 7)
#define UPOS  165    // UW*UH
#define DSTR  177    // D row stride (odd -> bank spread)
#define BITEMS (UPOS * 16)   // 2640 uint4 items per B half
#define NSLOT 6              // ceil(2640 / 512)

using f16x8 = __attribute__((ext_vector_type(8))) _Float16;
using f32x4 = __attribute__((ext_vector_type(4))) float;

__device__ __forceinline__ __half2 u2h2(unsigned u) {
    union { unsigned u; __half2 h; } v; v.u = u; return v.h;
}
__device__ __forceinline__ unsigned h22u(__half2 h) {
    union { unsigned u; __half2 h; } v; v.h = h; return v.u;
}
__device__ __forceinline__ f16x8 ldfrag(const ushort* p) {
    return __builtin_bit_cast(f16x8, *(const uint4*)p);
}
__device__ __forceinline__ void blend8(uint4 u, float w, float* a) {
    float2 m;
    m = __half22float2(u2h2(u.x)); a[0] += w * m.x; a[1] += w * m.y;
    m = __half22float2(u2h2(u.y)); a[2] += w * m.x; a[3] += w * m.y;
    m = __half22float2(u2h2(u.z)); a[4] += w * m.x; a[5] += w * m.y;
    m = __half22float2(u2h2(u.w)); a[6] += w * m.x; a[7] += w * m.y;
}
__device__ __forceinline__ uint4 pack8(const float* a) {
    uint4 o;
    o.x = h22u(__float22half2_rn(make_float2(a[0], a[1])));
    o.y = h22u(__float22half2_rn(make_float2(a[2], a[3])));
    o.z = h22u(__float22half2_rn(make_float2(a[4], a[5])));
    o.w = h22u(__float22half2_rn(make_float2(a[6], a[7])));
    return o;
}

// ---------------------------------------------------------------------------
// Kernel T (validated R7): pure coalesced transpose of f1 AND f2 into
// channel-last f16 [B, HW, C] (f1t, f2t) + c1 passthrough (out 0).
// grid = (128, 8), block = 256; LDS 2 x [32][65] fp32 tiles.
// ---------------------------------------------------------------------------
__global__ __launch_bounds__(256) void transpose_kernel(
    const float* __restrict__ f1, const float* __restrict__ f2,
    const float* __restrict__ c1, __half* __restrict__ f1t,
    __half* __restrict__ f2t, float* __restrict__ out0)
{
    __shared__ float s1[32][65];
    __shared__ float s2[32][65];

    const int t  = threadIdx.x;
    const int b  = blockIdx.x >> 6;
    const int nb = (blockIdx.x & 63) << 6;
    const int cc = blockIdx.y << 5;          // 32-channel slice

    if (blockIdx.y == 0 && t < 128) {
        const int idx = blockIdx.x * 128 + t;
        out0[idx] = c1[idx];
    }

    const int pix = t & 63;
    const int tq  = t >> 6;
    const int n   = nb + pix;

    const float* f2b = f2 + ((size_t)b * CCH + cc) * HW;
    const float* f1b = f1 + ((size_t)b * CCH + cc) * HW;

    #pragma unroll
    for (int j = 0; j < 8; ++j) {
        const int cl = tq * 8 + j;               // local channel 0..31
        s2[cl][pix] = f2b[(size_t)cl * HW + n];
        s1[cl][pix] = f1b[(size_t)cl * HW + n];
    }
    __syncthreads();

    const int lo = t & 7;                        // channel quad 0..7
    const int pq = t >> 3;                       // pixel 0..31
    ushort* o1 = (ushort*)f1t;
    ushort* o2 = (ushort*)f2t;
    #pragma unroll
    for (int j = 0; j < 2; ++j) {
        const int pix2 = j * 32 + pq;
        const int c4 = 4 * lo;
        const size_t base = ((size_t)(b * HW + nb + pix2)) * CCH + cc + c4;
        uint2 va, vb;
        va.x = h22u(__float22half2_rn(make_float2(s1[c4 + 0][pix2], s1[c4 + 1][pix2])));
        va.y = h22u(__float22half2_rn(make_float2(s1[c4 + 2][pix2], s1[c4 + 3][pix2])));
        vb.x = h22u(__float22half2_rn(make_float2(s2[c4 + 0][pix2], s2[c4 + 1][pix2])));
        vb.y = h22u(__float22half2_rn(make_float2(s2[c4 + 2][pix2], s2[c4 + 3][pix2])));
        *(uint2*)(o1 + base) = va;
        *(uint2*)(o2 + base) = vb;
    }
}

// ---------------------------------------------------------------------------
// Kernel C: tiled MFMA correlation with FUSED warp B-staging.
// Block = 4x8 pixel tile (32 px), 512 thr (8 waves), grid 256 (XCD-swizzled).
// Per-union-position warp meta (4 corner pixel offsets + 4 bilinear weights
// from c1, zero-padding masked) is computed by 165 threads into LDS; the
// B-stage loop loads 4 contiguous 512B corner vectors per position/chunk
// from UNWARPED f2t and blends in fp32 -> f16 fragment. Half-1 blends are
// kept in registers (T14) and ds_written after the half-0 MFMA barrier.
// ---------------------------------------------------------------------------
__global__ __launch_bounds__(512) void corr_fused_kernel(
    const __half* __restrict__ f1t, const __half* __restrict__ f2t,
    const float* __restrict__ c1, const float* __restrict__ c0,
    float* __restrict__ outc)
{
    __shared__ __align__(16) char RAW[16384 + 176 * 128 * 2];
    __shared__ float s_fx[32], s_fy[32];
    __shared__ int   s_lbx[32], s_lby[32];
    __shared__ float4 s_cw[UPOS];   // bilinear corner weights per union pos
    __shared__ int4   s_co[UPOS];   // corner pixel offsets per union pos

    ushort* A16 = (ushort*)RAW;
    ushort* B16 = (ushort*)(RAW + 16384);
    float*  Dex = (float*)(RAW + 16384);      // overlays B after compute

    const int t  = threadIdx.x;
    const int l  = t & 63;
    const int wv = t >> 6;

    // XCD-aware bijective swizzle: 256 = 8 * 32
    const int bid = blockIdx.x;
    const int swz = (bid & 7) * 32 + (bid >> 3);
    const int b   = swz >> 7;
    const int tau = swz & 127;
    const int ty  = tau >> 3, tx = tau & 7;
    const int n0  = ty * 256 + tx * 8;        // tile base pixel

    const ushort* f1u = (const ushort*)f1t + ((size_t)b * HW) * CCH;
    const ushort* f2u = (const ushort*)f2t + ((size_t)b * HW) * CCH;

    // ---- issue A loads first (independent of meta) ----
    const int r0 = t >> 5,         c0i = t & 31;
    const int r1 = (t + 512) >> 5, c1i = (t + 512) & 31;
    const int an0 = n0 + ((r0 >> 3) << 6) + (r0 & 7);
    const int an1 = n0 + ((r1 >> 3) << 6) + (r1 & 7);
    const uint4 av0 = *(const uint4*)(f1u + (size_t)an0 * CCH + c0i * 8);
    const uint4 av1 = *(const uint4*)(f1u + (size_t)an1 * CCH + c1i * 8);

    // ---- meta: every wave computes the span reduce redundantly ----
    float pcx = 0.f, pcy = 0.f;
    int ifx = 0, ify = 0;
    if (l < 32) {
        const int n = n0 + ((l >> 3) << 6) + (l & 7);
        pcx = c0[(b * 2 + 0) * HW + n];
        pcy = c0[(b * 2 + 1) * HW + n];
        ifx = (int)floorf(pcx);
        ify = (int)floorf(pcy);
    }
    int mnx = (l < 32) ? ifx : 0x7fffffff;
    int mxx = (l < 32) ? ifx : (-0x7fffffff - 1);
    int mny = (l < 32) ? ify : 0x7fffffff;
    int mxy = (l < 32) ? ify : (-0x7fffffff - 1);
    #pragma unroll
    for (int off = 1; off < 64; off <<= 1) {
        mnx = min(mnx, __shfl_xor(mnx, off, 64));
        mxx = max(mxx, __shfl_xor(mxx, off, 64));
        mny = min(mny, __shfl_xor(mny, off, 64));
        mxy = max(mxy, __shfl_xor(mxy, off, 64));
    }
    const int bx0 = mnx - 3, by0 = mny - 3;
    const int contained = (mxx - mnx <= 7) && (mxy - mny <= 3);

    if (wv == 0 && l < 32) {
        s_fx[l]  = pcx - floorf(pcx);
        s_fy[l]  = pcy - floorf(pcy);
        s_lbx[l] = ifx - mnx;
        s_lby[l] = ify - mny;
    }

    // ---- per-union-position warp meta (c1 bilinear corners/weights) ----
    if (t < UPOS) {
        const int wy = t / UW, wx = t - wy * UW;
        const int py = by0 + wy, px = bx0 + wx;
        float4 cw = {0.f, 0.f, 0.f, 0.f};
        int4   co = {0, 0, 0, 0};
        if (px >= 0 && px < WDIM && py >= 0 && py < WDIM) {
            const int np = py * WDIM + px;
            const float cx = c1[(b * 2 + 0) * HW + np];
            const float cy = c1[(b * 2 + 1) * HW + np];
            const float x0f = floorf(cx), y0f = floorf(cy);
            const float fx = cx - x0f, fy = cy - y0f;
            const int ix0 = (int)x0f, iy0 = (int)y0f;
            const int ix1 = ix0 + 1,  iy1 = iy0 + 1;
            float w00 = (1.f - fx) * (1.f - fy);
            float w01 = fx * (1.f - fy);
            float w10 = (1.f - fx) * fy;
            float w11 = fx * fy;
            if (ix0 < 0 || ix0 >= WDIM) { w00 = 0.f; w10 = 0.f; }
            if (ix1 < 0 || ix1 >= WDIM) { w01 = 0.f; w11 = 0.f; }
            if (iy0 < 0 || iy0 >= WDIM) { w00 = 0.f; w01 = 0.f; }
            if (iy1 < 0 || iy1 >= WDIM) { w10 = 0.f; w11 = 0.f; }
            const int xc0 = min(max(ix0, 0), WDIM - 1);
            const int xc1 = min(max(ix1, 0), WDIM - 1);
            const int yc0 = min(max(iy0, 0), WDIM - 1);
            const int yc1 = min(max(iy1, 0), WDIM - 1);
            cw = float4{w00, w01, w10, w11};
            co = int4{yc0 * WDIM + xc0, yc0 * WDIM + xc1,
                      yc1 * WDIM + xc0, yc1 * WDIM + xc1};
        }
        s_cw[t] = cw;
        s_co[t] = co;
    }
    __syncthreads();   // warp meta ready

    if (contained) {
        // ---- fused B-stage: blend 4 corners per (pos, chunk), both halves;
        //      half0 -> LDS now, half1 kept in registers (T14) ----
        uint4 b1r[NSLOT];
        int   bofs[NSLOT];
        #pragma unroll
        for (int k = 0; k < NSLOT; ++k) {
            const int idx = t + k * 512;
            bofs[k] = -1;
            b1r[k] = uint4{0u, 0u, 0u, 0u};
            uint4 h0 = uint4{0u, 0u, 0u, 0u};
            if (idx < BITEMS) {
                const int r = idx >> 4, c = idx & 15;
                bofs[k] = r * 128 + ((c ^ (r & 7)) << 3);
                const float4 cw = s_cw[r];
                const int4   co = s_co[r];
                const ushort* base = f2u + c * 8;
                float a0[8] = {0.f,0.f,0.f,0.f,0.f,0.f,0.f,0.f};
                float a1[8] = {0.f,0.f,0.f,0.f,0.f,0.f,0.f,0.f};
                const ushort* p0 = base + (size_t)co.x * CCH;
                const ushort* p1 = base + (size_t)co.y * CCH;
                const ushort* p2 = base + (size_t)co.z * CCH;
                const ushort* p3 = base + (size_t)co.w * CCH;
                blend8(*(const uint4*)(p0),       cw.x, a0);
                blend8(*(const uint4*)(p0 + 128), cw.x, a1);
                blend8(*(const uint4*)(p1),       cw.y, a0);
                blend8(*(const uint4*)(p1 + 128), cw.y, a1);
                blend8(*(const uint4*)(p2),       cw.z, a0);
                blend8(*(const uint4*)(p2 + 128), cw.z, a1);
                blend8(*(const uint4*)(p3),       cw.w, a0);
                blend8(*(const uint4*)(p3 + 128), cw.w, a1);
                h0 = pack8(a0);
                b1r[k] = pack8(a1);
            }
            if (bofs[k] >= 0) *(uint4*)(B16 + bofs[k]) = h0;
        }

        // ---- ds_write A ----
        *(uint4*)(A16 + r0 * 256 + ((c0i ^ (r0 & 7)) << 3)) = av0;
        *(uint4*)(A16 + r1 * 256 + ((c1i ^ (r1 & 7)) << 3)) = av1;
        __syncthreads();

        // ---- MFMA setup ----
        const int mt = wv & 1;          // m-tile (16 px)
        const int ng = wv >> 1;         // n-group
        const int nnt = (ng == 3) ? 2 : 3;
        int nt[3] = {ng, ng + 4, ng + 8};
        f32x4 acc[3];
        #pragma unroll
        for (int i = 0; i < 3; ++i) acc[i] = f32x4{0.f, 0.f, 0.f, 0.f};

        const int g    = l >> 4;
        const int arow = mt * 16 + (l & 15);
        const int axr  = arow & 7;

        // half 0
        {
            f16x8 af[4];
            #pragma unroll
            for (int s = 0; s < 4; ++s)
                af[s] = ldfrag(A16 + arow * 256 + (((s * 4 + g) ^ axr) << 3));
            #pragma unroll
            for (int i = 0; i < 3; ++i) if (i < nnt) {
                const int brow = nt[i] * 16 + (l & 15);
                const int bxr  = brow & 7;
                #pragma unroll
                for (int s = 0; s < 4; ++s) {
                    const f16x8 bf = ldfrag(B16 + brow * 128 + (((s * 4 + g) ^ bxr) << 3));
                    acc[i] = __builtin_amdgcn_mfma_f32_16x16x32_f16(af[s], bf, acc[i], 0, 0, 0);
                }
            }
        }
        __syncthreads();   // all B-half-0 reads done

        // ---- ds_write B half 1 (blended during stage, held in regs) ----
        #pragma unroll
        for (int k = 0; k < NSLOT; ++k)
            if (bofs[k] >= 0) *(uint4*)(B16 + bofs[k]) = b1r[k];
        __syncthreads();

        // half 1
        {
            f16x8 af[4];
            #pragma unroll
            for (int s = 0; s < 4; ++s)
                af[s] = ldfrag(A16 + arow * 256 + (((16 + s * 4 + g) ^ axr) << 3));
            #pragma unroll
            for (int i = 0; i < 3; ++i) if (i < nnt) {
                const int brow = nt[i] * 16 + (l & 15);
                const int bxr  = brow & 7;
                #pragma unroll
                for (int s = 0; s < 4; ++s) {
                    const f16x8 bf = ldfrag(B16 + brow * 128 + (((s * 4 + g) ^ bxr) << 3));
                    acc[i] = __builtin_amdgcn_mfma_f32_16x16x32_f16(af[s], bf, acc[i], 0, 0, 0);
                }
            }
        }
        __syncthreads();   // A,B dead -> D may overlay

        // ---- D -> LDS ----
        #pragma unroll
        for (int i = 0; i < 3; ++i) if (i < nnt) {
            #pragma unroll
            for (int r4 = 0; r4 < 4; ++r4) {
                Dex[(mt * 16 + (l >> 4) * 4 + r4) * DSTR + nt[i] * 16 + (l & 15)] = acc[i][r4];
            }
        }
        __syncthreads();

        // ---- output: bilinear combine of 4 D entries per (pixel, k) ----
        for (int idx = t; idx < 32 * KWIN; idx += 512) {
            const int p = idx & 31, k = idx >> 5;
            const int dyi = k / 7, dxi = k - dyi * 7;
            const int pos = (s_lby[p] + dyi) * UW + s_lbx[p] + dxi;
            const float* dr = Dex + p * DSTR + pos;
            const float d00 = dr[0], d01 = dr[1], d10 = dr[UW], d11 = dr[UW + 1];
            const float fx = s_fx[p], fy = s_fy[p];
            const float w00 = (1.f - fx) * (1.f - fy);
            const float w01 = fx * (1.f - fy);
            const float w10 = (1.f - fx) * fy;
            const float w11 = fx * fy;
            const float r = (w00 * d00 + w01 * d01 + w10 * d10 + w11 * d11) * 0.0625f;
            const int n = n0 + ((p >> 3) << 6) + (p & 7);
            outc[(size_t)(b * KWIN + k) * HW + n] = r;
        }
    } else {
        // ---- fallback: general coords, per-pixel gather, warp on the fly ----
        float* sDw = (float*)RAW + wv * 64;
        for (int p = wv; p < 32; p += 8) {
            const int n = n0 + ((p >> 3) << 6) + (p & 7);
            const float cx = c0[(b * 2 + 0) * HW + n];
            const float cy = c0[(b * 2 + 1) * HW + n];
            const float x0f = floorf(cx), y0f = floorf(cy);
            const float fx = cx - x0f, fy = cy - y0f;
            const int bx = (int)x0f - 3, by = (int)y0f - 3;
            const int ix = l & 7, iy = l >> 3;
            const int px = bx + ix, py = by + iy;
            float a = 0.f;
            if (px >= 0 && px < WDIM && py >= 0 && py < WDIM) {
                const int np = py * WDIM + px;
                const float wcx = c1[(b * 2 + 0) * HW + np];
                const float wcy = c1[(b * 2 + 1) * HW + np];
                const float wx0f = floorf(wcx), wy0f = floorf(wcy);
                const float gx = wcx - wx0f, gy = wcy - wy0f;
                const int jx0 = (int)wx0f, jy0 = (int)wy0f;
                const int jx1 = jx0 + 1,   jy1 = jy0 + 1;
                float w00 = (1.f - gx) * (1.f - gy);
                float w01 = gx * (1.f - gy);
                float w10 = (1.f - gx) * gy;
                float w11 = gx * gy;
                if (jx0 < 0 || jx0 >= WDIM) { w00 = 0.f; w10 = 0.f; }
                if (jx1 < 0 || jx1 >= WDIM) { w01 = 0.f; w11 = 0.f; }
                if (jy0 < 0 || jy0 >= WDIM) { w00 = 0.f; w01 = 0.f; }
                if (jy1 < 0 || jy1 >= WDIM) { w10 = 0.f; w11 = 0.f; }
                const int kx0 = min(max(jx0, 0), WDIM - 1);
                const int kx1 = min(max(jx1, 0), WDIM - 1);
                const int ky0 = min(max(jy0, 0), WDIM - 1);
                const int ky1 = min(max(jy1, 0), WDIM - 1);
                const ushort* qr = f1u + (size_t)n * CCH;
                const ushort* e0 = f2u + (size_t)(ky0 * WDIM + kx0) * CCH;
                const ushort* e1 = f2u + (size_t)(ky0 * WDIM + kx1) * CCH;
                const ushort* e2 = f2u + (size_t)(ky1 * WDIM + kx0) * CCH;
                const ushort* e3 = f2u + (size_t)(ky1 * WDIM + kx1) * CCH;
                for (int c = 0; c < 32; ++c) {
                    float w8[8] = {0.f,0.f,0.f,0.f,0.f,0.f,0.f,0.f};
                    blend8(*(const uint4*)(e0 + c * 8), w00, w8);
                    blend8(*(const uint4*)(e1 + c * 8), w01, w8);
                    blend8(*(const uint4*)(e2 + c * 8), w10, w8);
                    blend8(*(const uint4*)(e3 + c * 8), w11, w8);
                    const uint4 uq = *(const uint4*)(qr + c * 8);
                    float q8[8] = {0.f,0.f,0.f,0.f,0.f,0.f,0.f,0.f};
                    blend8(uq, 1.f, q8);
                    #pragma unroll
                    for (int e = 0; e < 8; ++e) a += q8[e] * w8[e];
                }
            }
            sDw[l] = a;   // same-wave producer/consumer
            const int k = l;
            if (k < KWIN) {
                const int dyi = k / 7, dxi = k - dyi * 7;
                const int s = dyi * 8 + dxi;
                const float d00 = sDw[s], d01 = sDw[s + 1];
                const float d10 = sDw[s + 8], d11 = sDw[s + 9];
                const float w00 = (1.f - fx) * (1.f - fy);
                const float w01 = fx * (1.f - fy);
                const float w10 = (1.f - fx) * fy;
                const float w11 = fx * fy;
                const float r = (w00 * d00 + w01 * d01 + w10 * d10 + w11 * d11) * 0.0625f;
                outc[(size_t)(b * KWIN + k) * HW + n] = r;
            }
        }
    }
}

extern "C" void kernel_launch(void* const* d_in, const int* in_sizes, int n_in,
                              void* d_out, int out_size, void* d_ws, size_t ws_size,
                              hipStream_t stream) {
    (void)in_sizes; (void)n_in; (void)out_size; (void)ws_size;
    const float* f1 = (const float*)d_in[0];
    const float* f2 = (const float*)d_in[1];
    const float* c1 = (const float*)d_in[2];
    const float* c0 = (const float*)d_in[3];
    float* out = (float*)d_out;

    const size_t PLANE = (size_t)BATCH * HW * CCH;   // 2M halfs = 4 MB
    __half* f1t = (__half*)d_ws;           // [B,HW,C] f16
    __half* f2t = f1t + PLANE;             // plain   [B,HW,C] f16

    dim3 g1(BATCH * (HW / 64), CCH / 32);
    transpose_kernel<<<g1, 256, 0, stream>>>(f1, f2, c1, f1t, f2t, out);

    corr_fused_kernel<<<(BATCH * HW) / 32, 512, 0, stream>>>(
        f1t, f2t, c1, c0, out + BATCH * 2 * HW);
}

// Round 10
// 19.018 us; speedup vs baseline: 5.1083x; 1.0523x over previous
//
#include <hip/hip_runtime.h>
#include <hip/hip_fp16.h>

#define BATCH 2
#define CCH   256
#define WDIM  64
#define HW    4096   // 64*64
#define KWIN  49

// corr tile geometry: 8 wide (x) x 4 tall (y) = 32 pixels per block
#define UW    15     // union window cols  (8 px x-span + 7)
#define UH    11     // union window rows  (4 px y-span + 7)
#define UPOS  165    // UW*UH
#define DSTR  177    // D row stride (odd -> bank spread)
#define BITEMS (UPOS * 16)   // 2640 uint4 items per B half
#define NSLOT 6              // ceil(2640 / 512)
#define BBYTES (176 * 128 * 2)   // one B half buffer: 45056 B

using f16x8 = __attribute__((ext_vector_type(8))) _Float16;
using f32x4 = __attribute__((ext_vector_type(4))) float;

__device__ __forceinline__ __half2 u2h2(unsigned u) {
    union { unsigned u; __half2 h; } v; v.u = u; return v.h;
}
__device__ __forceinline__ unsigned h22u(__half2 h) {
    union { unsigned u; __half2 h; } v; v.h = h; return v.u;
}
__device__ __forceinline__ f16x8 ldfrag(const ushort* p) {
    return __builtin_bit_cast(f16x8, *(const uint4*)p);
}
__device__ __forceinline__ void blend8(uint4 u, float w, float* a) {
    float2 m;
    m = __half22float2(u2h2(u.x)); a[0] += w * m.x; a[1] += w * m.y;
    m = __half22float2(u2h2(u.y)); a[2] += w * m.x; a[3] += w * m.y;
    m = __half22float2(u2h2(u.z)); a[4] += w * m.x; a[5] += w * m.y;
    m = __half22float2(u2h2(u.w)); a[6] += w * m.x; a[7] += w * m.y;
}
// packed f16 4-corner blend of one 2-channel unit
__device__ __forceinline__ unsigned h2fma4(unsigned a, unsigned b, unsigned c,
                                           unsigned d, __half2 w0, __half2 w1,
                                           __half2 w2, __half2 w3) {
    __half2 acc = __hmul2(w0, u2h2(a));
    acc = __hfma2(w1, u2h2(b), acc);
    acc = __hfma2(w2, u2h2(c), acc);
    acc = __hfma2(w3, u2h2(d), acc);
    return h22u(acc);
}

// ---------------------------------------------------------------------------
// Kernel T (validated R7/R9): pure coalesced transpose of f1 AND f2 into
// channel-last f16 [B, HW, C] (f1t, f2t) + c1 passthrough (out 0).
// grid = (128, 8), block = 256; LDS 2 x [32][65] fp32 tiles.
// ---------------------------------------------------------------------------
__global__ __launch_bounds__(256) void transpose_kernel(
    const float* __restrict__ f1, const float* __restrict__ f2,
    const float* __restrict__ c1, __half* __restrict__ f1t,
    __half* __restrict__ f2t, float* __restrict__ out0)
{
    __shared__ float s1[32][65];
    __shared__ float s2[32][65];

    const int t  = threadIdx.x;
    const int b  = blockIdx.x >> 6;
    const int nb = (blockIdx.x & 63) << 6;
    const int cc = blockIdx.y << 5;          // 32-channel slice

    if (blockIdx.y == 0 && t < 128) {
        const int idx = blockIdx.x * 128 + t;
        out0[idx] = c1[idx];
    }

    const int pix = t & 63;
    const int tq  = t >> 6;
    const int n   = nb + pix;

    const float* f2b = f2 + ((size_t)b * CCH + cc) * HW;
    const float* f1b = f1 + ((size_t)b * CCH + cc) * HW;

    #pragma unroll
    for (int j = 0; j < 8; ++j) {
        const int cl = tq * 8 + j;               // local channel 0..31
        s2[cl][pix] = f2b[(size_t)cl * HW + n];
        s1[cl][pix] = f1b[(size_t)cl * HW + n];
    }
    __syncthreads();

    const int lo = t & 7;                        // channel quad 0..7
    const int pq = t >> 3;                       // pixel 0..31
    ushort* o1 = (ushort*)f1t;
    ushort* o2 = (ushort*)f2t;
    #pragma unroll
    for (int j = 0; j < 2; ++j) {
        const int pix2 = j * 32 + pq;
        const int c4 = 4 * lo;
        const size_t base = ((size_t)(b * HW + nb + pix2)) * CCH + cc + c4;
        uint2 va, vb;
        va.x = h22u(__float22half2_rn(make_float2(s1[c4 + 0][pix2], s1[c4 + 1][pix2])));
        va.y = h22u(__float22half2_rn(make_float2(s1[c4 + 2][pix2], s1[c4 + 3][pix2])));
        vb.x = h22u(__float22half2_rn(make_float2(s2[c4 + 0][pix2], s2[c4 + 1][pix2])));
        vb.y = h22u(__float22half2_rn(make_float2(s2[c4 + 2][pix2], s2[c4 + 3][pix2])));
        *(uint2*)(o1 + base) = va;
        *(uint2*)(o2 + base) = vb;
    }
}

// ---------------------------------------------------------------------------
// Kernel C: tiled MFMA correlation with fused warp B-staging, pipelined.
// vs R9: (1) stage loop software-pipelined (double-buffered regs, slot k+1
// loads issued before slot k blend -> ~16 loads in flight); (2) BOTH B
// halves get their own LDS buffer (B0/B1, 112 KB total) -> single stage
// barrier, MFMA h0+h1 back-to-back, 2 fewer barriers; (3) blend in packed
// f16 (__hfma2) -> half the stage VALU.
// ---------------------------------------------------------------------------
__global__ __launch_bounds__(512) void corr_fused_kernel(
    const __half* __restrict__ f1t, const __half* __restrict__ f2t,
    const float* __restrict__ c1, const float* __restrict__ c0,
    float* __restrict__ outc)
{
    __shared__ __align__(16) char RAW[16384 + 2 * BBYTES];   // A | B0 | B1
    __shared__ float s_fx[32], s_fy[32];
    __shared__ int   s_lbx[32], s_lby[32];
    __shared__ float4 s_cw[UPOS];   // bilinear corner weights per union pos
    __shared__ int4   s_co[UPOS];   // corner pixel offsets per union pos

    ushort* A16 = (ushort*)RAW;
    ushort* B0  = (ushort*)(RAW + 16384);
    ushort* B1  = (ushort*)(RAW + 16384 + BBYTES);
    float*  Dex = (float*)(RAW + 16384);      // overlays B0 after compute

    const int t  = threadIdx.x;
    const int l  = t & 63;
    const int wv = t >> 6;

    // XCD-aware bijective swizzle: 256 = 8 * 32
    const int bid = blockIdx.x;
    const int swz = (bid & 7) * 32 + (bid >> 3);
    const int b   = swz >> 7;
    const int tau = swz & 127;
    const int ty  = tau >> 3, tx = tau & 7;
    const int n0  = ty * 256 + tx * 8;        // tile base pixel

    const ushort* f1u = (const ushort*)f1t + ((size_t)b * HW) * CCH;
    const ushort* f2u = (const ushort*)f2t + ((size_t)b * HW) * CCH;

    // ---- issue A loads first (independent of meta) ----
    const int r0 = t >> 5,         c0i = t & 31;
    const int r1 = (t + 512) >> 5, c1i = (t + 512) & 31;
    const int an0 = n0 + ((r0 >> 3) << 6) + (r0 & 7);
    const int an1 = n0 + ((r1 >> 3) << 6) + (r1 & 7);
    const uint4 av0 = *(const uint4*)(f1u + (size_t)an0 * CCH + c0i * 8);
    const uint4 av1 = *(const uint4*)(f1u + (size_t)an1 * CCH + c1i * 8);

    // ---- meta: every wave computes the span reduce redundantly ----
    float pcx = 0.f, pcy = 0.f;
    int ifx = 0, ify = 0;
    if (l < 32) {
        const int n = n0 + ((l >> 3) << 6) + (l & 7);
        pcx = c0[(b * 2 + 0) * HW + n];
        pcy = c0[(b * 2 + 1) * HW + n];
        ifx = (int)floorf(pcx);
        ify = (int)floorf(pcy);
    }
    int mnx = (l < 32) ? ifx : 0x7fffffff;
    int mxx = (l < 32) ? ifx : (-0x7fffffff - 1);
    int mny = (l < 32) ? ify : 0x7fffffff;
    int mxy = (l < 32) ? ify : (-0x7fffffff - 1);
    #pragma unroll
    for (int off = 1; off < 64; off <<= 1) {
        mnx = min(mnx, __shfl_xor(mnx, off, 64));
        mxx = max(mxx, __shfl_xor(mxx, off, 64));
        mny = min(mny, __shfl_xor(mny, off, 64));
        mxy = max(mxy, __shfl_xor(mxy, off, 64));
    }
    const int bx0 = mnx - 3, by0 = mny - 3;
    const int contained = (mxx - mnx <= 7) && (mxy - mny <= 3);

    if (wv == 0 && l < 32) {
        s_fx[l]  = pcx - floorf(pcx);
        s_fy[l]  = pcy - floorf(pcy);
        s_lbx[l] = ifx - mnx;
        s_lby[l] = ify - mny;
    }

    // ---- per-union-position warp meta (c1 bilinear corners/weights) ----
    if (t < UPOS) {
        const int wy = t / UW, wx = t - wy * UW;
        const int py = by0 + wy, px = bx0 + wx;
        float4 cw = {0.f, 0.f, 0.f, 0.f};
        int4   co = {0, 0, 0, 0};
        if (px >= 0 && px < WDIM && py >= 0 && py < WDIM) {
            const int np = py * WDIM + px;
            const float cx = c1[(b * 2 + 0) * HW + np];
            const float cy = c1[(b * 2 + 1) * HW + np];
            const float x0f = floorf(cx), y0f = floorf(cy);
            const float fx = cx - x0f, fy = cy - y0f;
            const int ix0 = (int)x0f, iy0 = (int)y0f;
            const int ix1 = ix0 + 1,  iy1 = iy0 + 1;
            float w00 = (1.f - fx) * (1.f - fy);
            float w01 = fx * (1.f - fy);
            float w10 = (1.f - fx) * fy;
            float w11 = fx * fy;
            if (ix0 < 0 || ix0 >= WDIM) { w00 = 0.f; w10 = 0.f; }
            if (ix1 < 0 || ix1 >= WDIM) { w01 = 0.f; w11 = 0.f; }
            if (iy0 < 0 || iy0 >= WDIM) { w00 = 0.f; w01 = 0.f; }
            if (iy1 < 0 || iy1 >= WDIM) { w10 = 0.f; w11 = 0.f; }
            const int xc0 = min(max(ix0, 0), WDIM - 1);
            const int xc1 = min(max(ix1, 0), WDIM - 1);
            const int yc0 = min(max(iy0, 0), WDIM - 1);
            const int yc1 = min(max(iy1, 0), WDIM - 1);
            cw = float4{w00, w01, w10, w11};
            co = int4{yc0 * WDIM + xc0, yc0 * WDIM + xc1,
                      yc1 * WDIM + xc0, yc1 * WDIM + xc1};
        }
        s_cw[t] = cw;
        s_co[t] = co;
    }

    // ---- ds_write A (waits only on the A loads; overlaps meta) ----
    *(uint4*)(A16 + r0 * 256 + ((c0i ^ (r0 & 7)) << 3)) = av0;
    *(uint4*)(A16 + r1 * 256 + ((c1i ^ (r1 & 7)) << 3)) = av1;

    __syncthreads();   // warp meta + A ready

    if (contained) {
        // ---- pipelined fused B-stage: double-buffered 8-load slots ----
        uint4   v0[2][4], v1[2][4];    // [buf][corner], half 0 / half 1
        __half2 wb[2][4];
        int     ob[2];

        auto issueSlot = [&](int k, int buf) {
            const int idx = t + k * 512;
            ob[buf] = -1;
            if (idx < BITEMS) {
                const int r = idx >> 4, c = idx & 15;
                ob[buf] = r * 128 + ((c ^ (r & 7)) << 3);
                const float4 cw = s_cw[r];
                const int4   co = s_co[r];
                wb[buf][0] = __float2half2_rn(cw.x);
                wb[buf][1] = __float2half2_rn(cw.y);
                wb[buf][2] = __float2half2_rn(cw.z);
                wb[buf][3] = __float2half2_rn(cw.w);
                const ushort* base = f2u + c * 8;
                const ushort* p0 = base + (size_t)co.x * CCH;
                const ushort* p1 = base + (size_t)co.y * CCH;
                const ushort* p2 = base + (size_t)co.z * CCH;
                const ushort* p3 = base + (size_t)co.w * CCH;
                v0[buf][0] = *(const uint4*)p0;  v1[buf][0] = *(const uint4*)(p0 + 128);
                v0[buf][1] = *(const uint4*)p1;  v1[buf][1] = *(const uint4*)(p1 + 128);
                v0[buf][2] = *(const uint4*)p2;  v1[buf][2] = *(const uint4*)(p2 + 128);
                v0[buf][3] = *(const uint4*)p3;  v1[buf][3] = *(const uint4*)(p3 + 128);
            }
        };

        issueSlot(0, 0);
        #pragma unroll
        for (int k = 0; k < NSLOT; ++k) {
            const int cb = k & 1;
            if (k + 1 < NSLOT) issueSlot(k + 1, cb ^ 1);
            if (ob[cb] >= 0) {
                const __half2 w0 = wb[cb][0], w1 = wb[cb][1];
                const __half2 w2 = wb[cb][2], w3 = wb[cb][3];
                uint4 o0, o1;
                o0.x = h2fma4(v0[cb][0].x, v0[cb][1].x, v0[cb][2].x, v0[cb][3].x, w0, w1, w2, w3);
                o0.y = h2fma4(v0[cb][0].y, v0[cb][1].y, v0[cb][2].y, v0[cb][3].y, w0, w1, w2, w3);
                o0.z = h2fma4(v0[cb][0].z, v0[cb][1].z, v0[cb][2].z, v0[cb][3].z, w0, w1, w2, w3);
                o0.w = h2fma4(v0[cb][0].w, v0[cb][1].w, v0[cb][2].w, v0[cb][3].w, w0, w1, w2, w3);
                o1.x = h2fma4(v1[cb][0].x, v1[cb][1].x, v1[cb][2].x, v1[cb][3].x, w0, w1, w2, w3);
                o1.y = h2fma4(v1[cb][0].y, v1[cb][1].y, v1[cb][2].y, v1[cb][3].y, w0, w1, w2, w3);
                o1.z = h2fma4(v1[cb][0].z, v1[cb][1].z, v1[cb][2].z, v1[cb][3].z, w0, w1, w2, w3);
                o1.w = h2fma4(v1[cb][0].w, v1[cb][1].w, v1[cb][2].w, v1[cb][3].w, w0, w1, w2, w3);
                *(uint4*)(B0 + ob[cb]) = o0;
                *(uint4*)(B1 + ob[cb]) = o1;
            }
        }
        __syncthreads();   // A, B0, B1 all staged

        // ---- MFMA: both halves back-to-back ----
        const int mt = wv & 1;          // m-tile (16 px)
        const int ng = wv >> 1;         // n-group
        const int nnt = (ng == 3) ? 2 : 3;
        int nt[3] = {ng, ng + 4, ng + 8};
        f32x4 acc[3];
        #pragma unroll
        for (int i = 0; i < 3; ++i) acc[i] = f32x4{0.f, 0.f, 0.f, 0.f};

        const int g    = l >> 4;
        const int arow = mt * 16 + (l & 15);
        const int axr  = arow & 7;

        {
            f16x8 af[8];
            #pragma unroll
            for (int s = 0; s < 4; ++s) {
                af[s]     = ldfrag(A16 + arow * 256 + (((s * 4 + g) ^ axr) << 3));
                af[4 + s] = ldfrag(A16 + arow * 256 + (((16 + s * 4 + g) ^ axr) << 3));
            }
            #pragma unroll
            for (int i = 0; i < 3; ++i) if (i < nnt) {
                const int brow = nt[i] * 16 + (l & 15);
                const int bxr  = brow & 7;
                #pragma unroll
                for (int s = 0; s < 4; ++s) {
                    const f16x8 bf0 = ldfrag(B0 + brow * 128 + (((s * 4 + g) ^ bxr) << 3));
                    acc[i] = __builtin_amdgcn_mfma_f32_16x16x32_f16(af[s], bf0, acc[i], 0, 0, 0);
                    const f16x8 bf1 = ldfrag(B1 + brow * 128 + (((s * 4 + g) ^ bxr) << 3));
                    acc[i] = __builtin_amdgcn_mfma_f32_16x16x32_f16(af[4 + s], bf1, acc[i], 0, 0, 0);
                }
            }
        }
        __syncthreads();   // A,B dead -> D may overlay

        // ---- D -> LDS ----
        #pragma unroll
        for (int i = 0; i < 3; ++i) if (i < nnt) {
            #pragma unroll
            for (int r4 = 0; r4 < 4; ++r4) {
                Dex[(mt * 16 + (l >> 4) * 4 + r4) * DSTR + nt[i] * 16 + (l & 15)] = acc[i][r4];
            }
        }
        __syncthreads();

        // ---- output: bilinear combine of 4 D entries per (pixel, k) ----
        for (int idx = t; idx < 32 * KWIN; idx += 512) {
            const int p = idx & 31, k = idx >> 5;
            const int dyi = k / 7, dxi = k - dyi * 7;
            const int pos = (s_lby[p] + dyi) * UW + s_lbx[p] + dxi;
            const float* dr = Dex + p * DSTR + pos;
            const float d00 = dr[0], d01 = dr[1], d10 = dr[UW], d11 = dr[UW + 1];
            const float fx = s_fx[p], fy = s_fy[p];
            const float w00 = (1.f - fx) * (1.f - fy);
            const float w01 = fx * (1.f - fy);
            const float w10 = (1.f - fx) * fy;
            const float w11 = fx * fy;
            const float r = (w00 * d00 + w01 * d01 + w10 * d10 + w11 * d11) * 0.0625f;
            const int n = n0 + ((p >> 3) << 6) + (p & 7);
            outc[(size_t)(b * KWIN + k) * HW + n] = r;
        }
    } else {
        // ---- fallback: general coords, per-pixel gather, warp on the fly ----
        float* sDw = (float*)RAW + wv * 64;
        for (int p = wv; p < 32; p += 8) {
            const int n = n0 + ((p >> 3) << 6) + (p & 7);
            const float cx = c0[(b * 2 + 0) * HW + n];
            const float cy = c0[(b * 2 + 1) * HW + n];
            const float x0f = floorf(cx), y0f = floorf(cy);
            const float fx = cx - x0f, fy = cy - y0f;
            const int bx = (int)x0f - 3, by = (int)y0f - 3;
            const int ix = l & 7, iy = l >> 3;
            const int px = bx + ix, py = by + iy;
            float a = 0.f;
            if (px >= 0 && px < WDIM && py >= 0 && py < WDIM) {
                const int np = py * WDIM + px;
                const float wcx = c1[(b * 2 + 0) * HW + np];
                const float wcy = c1[(b * 2 + 1) * HW + np];
                const float wx0f = floorf(wcx), wy0f = floorf(wcy);
                const float gx = wcx - wx0f, gy = wcy - wy0f;
                const int jx0 = (int)wx0f, jy0 = (int)wy0f;
                const int jx1 = jx0 + 1,   jy1 = jy0 + 1;
                float w00 = (1.f - gx) * (1.f - gy);
                float w01 = gx * (1.f - gy);
                float w10 = (1.f - gx) * gy;
                float w11 = gx * gy;
                if (jx0 < 0 || jx0 >= WDIM) { w00 = 0.f; w10 = 0.f; }
                if (jx1 < 0 || jx1 >= WDIM) { w01 = 0.f; w11 = 0.f; }
                if (jy0 < 0 || jy0 >= WDIM) { w00 = 0.f; w01 = 0.f; }
                if (jy1 < 0 || jy1 >= WDIM) { w10 = 0.f; w11 = 0.f; }
                const int kx0 = min(max(jx0, 0), WDIM - 1);
                const int kx1 = min(max(jx1, 0), WDIM - 1);
                const int ky0 = min(max(jy0, 0), WDIM - 1);
                const int ky1 = min(max(jy1, 0), WDIM - 1);
                const ushort* qr = f1u + (size_t)n * CCH;
                const ushort* e0 = f2u + (size_t)(ky0 * WDIM + kx0) * CCH;
                const ushort* e1 = f2u + (size_t)(ky0 * WDIM + kx1) * CCH;
                const ushort* e2 = f2u + (size_t)(ky1 * WDIM + kx0) * CCH;
                const ushort* e3 = f2u + (size_t)(ky1 * WDIM + kx1) * CCH;
                for (int c = 0; c < 32; ++c) {
                    float w8[8] = {0.f,0.f,0.f,0.f,0.f,0.f,0.f,0.f};
                    blend8(*(const uint4*)(e0 + c * 8), w00, w8);
                    blend8(*(const uint4*)(e1 + c * 8), w01, w8);
                    blend8(*(const uint4*)(e2 + c * 8), w10, w8);
                    blend8(*(const uint4*)(e3 + c * 8), w11, w8);
                    const uint4 uq = *(const uint4*)(qr + c * 8);
                    float q8[8] = {0.f,0.f,0.f,0.f,0.f,0.f,0.f,0.f};
                    blend8(uq, 1.f, q8);
                    #pragma unroll
                    for (int e = 0; e < 8; ++e) a += q8[e] * w8[e];
                }
            }
            sDw[l] = a;   // same-wave producer/consumer
            const int k = l;
            if (k < KWIN) {
                const int dyi = k / 7, dxi = k - dyi * 7;
                const int s = dyi * 8 + dxi;
                const float d00 = sDw[s], d01 = sDw[s + 1];
                const float d10 = sDw[s + 8], d11 = sDw[s + 9];
                const float w00 = (1.f - fx) * (1.f - fy);
                const float w01 = fx * (1.f - fy);
                const float w10 = (1.f - fx) * fy;
                const float w11 = fx * fy;
                const float r = (w00 * d00 + w01 * d01 + w10 * d10 + w11 * d11) * 0.0625f;
                outc[(size_t)(b * KWIN + k) * HW + n] = r;
            }
        }
    }
}

extern "C" void kernel_launch(void* const* d_in, const int* in_sizes, int n_in,
                              void* d_out, int out_size, void* d_ws, size_t ws_size,
                              hipStream_t stream) {
    (void)in_sizes; (void)n_in; (void)out_size; (void)ws_size;
    const float* f1 = (const float*)d_in[0];
    const float* f2 = (const float*)d_in[1];
    const float* c1 = (const float*)d_in[2];
    const float* c0 = (const float*)d_in[3];
    float* out = (float*)d_out;

    const size_t PLANE = (size_t)BATCH * HW * CCH;   // 2M halfs = 4 MB
    __half* f1t = (__half*)d_ws;           // [B,HW,C] f16
    __half* f2t = f1t + PLANE;             // plain   [B,HW,C] f16

    dim3 g1(BATCH * (HW / 64), CCH / 32);
    transpose_kernel<<<g1, 256, 0, stream>>>(f1, f2, c1, f1t, f2t, out);

    corr_fused_kernel<<<(BATCH * HW) / 32, 512, 0, stream>>>(
        f1t, f2t, c1, c0, out + BATCH * 2 * HW);
}

// Round 11
// 18.849 us; speedup vs baseline: 5.1541x; 1.0090x over previous
//
#include <hip/hip_runtime.h>
#include <hip/hip_fp16.h>

#define BATCH 2
#define CCH   256
#define WDIM  64
#define HW    4096   // 64*64
#define KWIN  49

// corr tile geometry: 8 wide (x) x 4 tall (y) = 32 pixels per block
#define UW    15     // union window cols  (8 px x-span + 7)
#define UH    11     // union window rows  (4 px y-span + 7)
#define UPOS  165    // UW*UH
#define DSTR  177    // D row stride (odd -> bank spread)
#define BITEMS (UPOS * 16)   // 2640 uint4 items per B half
#define NSLOT 6              // ceil(2640 / 512)
#define BBYTES (176 * 128 * 2)   // one B half buffer: 45056 B

using f16x8 = __attribute__((ext_vector_type(8))) _Float16;
using f32x4 = __attribute__((ext_vector_type(4))) float;

__device__ __forceinline__ __half2 u2h2(unsigned u) {
    union { unsigned u; __half2 h; } v; v.u = u; return v.h;
}
__device__ __forceinline__ unsigned h22u(__half2 h) {
    union { unsigned u; __half2 h; } v; v.h = h; return v.u;
}
__device__ __forceinline__ f16x8 ldfrag(const ushort* p) {
    return __builtin_bit_cast(f16x8, *(const uint4*)p);
}
__device__ __forceinline__ void blend8(uint4 u, float w, float* a) {
    float2 m;
    m = __half22float2(u2h2(u.x)); a[0] += w * m.x; a[1] += w * m.y;
    m = __half22float2(u2h2(u.y)); a[2] += w * m.x; a[3] += w * m.y;
    m = __half22float2(u2h2(u.z)); a[4] += w * m.x; a[5] += w * m.y;
    m = __half22float2(u2h2(u.w)); a[6] += w * m.x; a[7] += w * m.y;
}
// packed f16 4-corner blend of one 2-channel unit
__device__ __forceinline__ unsigned h2fma4(unsigned a, unsigned b, unsigned c,
                                           unsigned d, __half2 w0, __half2 w1,
                                           __half2 w2, __half2 w3) {
    __half2 acc = __hmul2(w0, u2h2(a));
    acc = __hfma2(w1, u2h2(b), acc);
    acc = __hfma2(w2, u2h2(c), acc);
    acc = __hfma2(w3, u2h2(d), acc);
    return h22u(acc);
}

// ---------------------------------------------------------------------------
// Kernel T: coalesced transpose of f2 ONLY into channel-last f16 [B, HW, C]
// (f2t) + c1 passthrough (out 0). f1 is consumed directly by kernel C now.
// grid = (128, 8), block = 256; LDS [32][65] fp32 tile.
// ---------------------------------------------------------------------------
__global__ __launch_bounds__(256) void transpose_kernel(
    const float* __restrict__ f2, const float* __restrict__ c1,
    __half* __restrict__ f2t, float* __restrict__ out0)
{
    __shared__ float s2[32][65];

    const int t  = threadIdx.x;
    const int b  = blockIdx.x >> 6;
    const int nb = (blockIdx.x & 63) << 6;
    const int cc = blockIdx.y << 5;          // 32-channel slice

    if (blockIdx.y == 0 && t < 128) {
        const int idx = blockIdx.x * 128 + t;
        out0[idx] = c1[idx];
    }

    const int pix = t & 63;
    const int tq  = t >> 6;
    const int n   = nb + pix;

    const float* f2b = f2 + ((size_t)b * CCH + cc) * HW;

    #pragma unroll
    for (int j = 0; j < 8; ++j) {
        const int cl = tq * 8 + j;               // local channel 0..31
        s2[cl][pix] = f2b[(size_t)cl * HW + n];
    }
    __syncthreads();

    const int lo = t & 7;                        // channel quad 0..7
    const int pq = t >> 3;                       // pixel 0..31
    ushort* o2 = (ushort*)f2t;
    #pragma unroll
    for (int j = 0; j < 2; ++j) {
        const int pix2 = j * 32 + pq;
        const int c4 = 4 * lo;
        const size_t base = ((size_t)(b * HW + nb + pix2)) * CCH + cc + c4;
        uint2 vb;
        vb.x = h22u(__float22half2_rn(make_float2(s2[c4 + 0][pix2], s2[c4 + 1][pix2])));
        vb.y = h22u(__float22half2_rn(make_float2(s2[c4 + 2][pix2], s2[c4 + 3][pix2])));
        *(uint2*)(o2 + base) = vb;
    }
}

// ---------------------------------------------------------------------------
// Kernel C: tiled MFMA correlation with fused warp B-staging (R10 pipeline).
// vs R10: A-fragment staged DIRECTLY from channel-major fp32 f1 (4 float4
// loads/thread, f16 cvt in-register, swizzled scalar ds_writes) -- removes
// the f1 path from kernel T entirely (same RNE rounding, identical values).
// ---------------------------------------------------------------------------
__global__ __launch_bounds__(512) void corr_fused_kernel(
    const float* __restrict__ f1, const __half* __restrict__ f2t,
    const float* __restrict__ c1, const float* __restrict__ c0,
    float* __restrict__ outc)
{
    __shared__ __align__(16) char RAW[16384 + 2 * BBYTES];   // A | B0 | B1
    __shared__ float s_fx[32], s_fy[32];
    __shared__ int   s_lbx[32], s_lby[32];
    __shared__ float4 s_cw[UPOS];   // bilinear corner weights per union pos
    __shared__ int4   s_co[UPOS];   // corner pixel offsets per union pos

    ushort* A16 = (ushort*)RAW;
    ushort* B0  = (ushort*)(RAW + 16384);
    ushort* B1  = (ushort*)(RAW + 16384 + BBYTES);
    float*  Dex = (float*)(RAW + 16384);      // overlays B0 after compute

    const int t  = threadIdx.x;
    const int l  = t & 63;
    const int wv = t >> 6;

    // XCD-aware bijective swizzle: 256 = 8 * 32
    const int bid = blockIdx.x;
    const int swz = (bid & 7) * 32 + (bid >> 3);
    const int b   = swz >> 7;
    const int tau = swz & 127;
    const int ty  = tau >> 3, tx = tau & 7;
    const int n0  = ty * 256 + tx * 8;        // tile base pixel

    const float*  f1f = f1 + ((size_t)b * CCH) * HW;
    const ushort* f2u = (const ushort*)f2t + ((size_t)b * HW) * CCH;

    // ---- issue A loads first (channel-major fp32, 4 float4 / thread) ----
    float4 avf[4];
    #pragma unroll
    for (int k = 0; k < 4; ++k) {
        const int i = t + (k << 9);
        const int c = i >> 3;
        const int r = (i >> 1) & 3;
        const int q = i & 1;
        avf[k] = *(const float4*)(f1f + (size_t)c * HW +
                                  ((ty * 4 + r) * 64 + tx * 8 + q * 4));
    }

    // ---- meta: every wave computes the span reduce redundantly ----
    float pcx = 0.f, pcy = 0.f;
    int ifx = 0, ify = 0;
    if (l < 32) {
        const int n = n0 + ((l >> 3) << 6) + (l & 7);
        pcx = c0[(b * 2 + 0) * HW + n];
        pcy = c0[(b * 2 + 1) * HW + n];
        ifx = (int)floorf(pcx);
        ify = (int)floorf(pcy);
    }
    int mnx = (l < 32) ? ifx : 0x7fffffff;
    int mxx = (l < 32) ? ifx : (-0x7fffffff - 1);
    int mny = (l < 32) ? ify : 0x7fffffff;
    int mxy = (l < 32) ? ify : (-0x7fffffff - 1);
    #pragma unroll
    for (int off = 1; off < 64; off <<= 1) {
        mnx = min(mnx, __shfl_xor(mnx, off, 64));
        mxx = max(mxx, __shfl_xor(mxx, off, 64));
        mny = min(mny, __shfl_xor(mny, off, 64));
        mxy = max(mxy, __shfl_xor(mxy, off, 64));
    }
    const int bx0 = mnx - 3, by0 = mny - 3;
    const int contained = (mxx - mnx <= 7) && (mxy - mny <= 3);

    if (wv == 0 && l < 32) {
        s_fx[l]  = pcx - floorf(pcx);
        s_fy[l]  = pcy - floorf(pcy);
        s_lbx[l] = ifx - mnx;
        s_lby[l] = ify - mny;
    }

    // ---- per-union-position warp meta (c1 bilinear corners/weights) ----
    if (t < UPOS) {
        const int wy = t / UW, wx = t - wy * UW;
        const int py = by0 + wy, px = bx0 + wx;
        float4 cw = {0.f, 0.f, 0.f, 0.f};
        int4   co = {0, 0, 0, 0};
        if (px >= 0 && px < WDIM && py >= 0 && py < WDIM) {
            const int np = py * WDIM + px;
            const float cx = c1[(b * 2 + 0) * HW + np];
            const float cy = c1[(b * 2 + 1) * HW + np];
            const float x0f = floorf(cx), y0f = floorf(cy);
            const float fx = cx - x0f, fy = cy - y0f;
            const int ix0 = (int)x0f, iy0 = (int)y0f;
            const int ix1 = ix0 + 1,  iy1 = iy0 + 1;
            float w00 = (1.f - fx) * (1.f - fy);
            float w01 = fx * (1.f - fy);
            float w10 = (1.f - fx) * fy;
            float w11 = fx * fy;
            if (ix0 < 0 || ix0 >= WDIM) { w00 = 0.f; w10 = 0.f; }
            if (ix1 < 0 || ix1 >= WDIM) { w01 = 0.f; w11 = 0.f; }
            if (iy0 < 0 || iy0 >= WDIM) { w00 = 0.f; w01 = 0.f; }
            if (iy1 < 0 || iy1 >= WDIM) { w10 = 0.f; w11 = 0.f; }
            const int xc0 = min(max(ix0, 0), WDIM - 1);
            const int xc1 = min(max(ix1, 0), WDIM - 1);
            const int yc0 = min(max(iy0, 0), WDIM - 1);
            const int yc1 = min(max(iy1, 0), WDIM - 1);
            cw = float4{w00, w01, w10, w11};
            co = int4{yc0 * WDIM + xc0, yc0 * WDIM + xc1,
                      yc1 * WDIM + xc0, yc1 * WDIM + xc1};
        }
        s_cw[t] = cw;
        s_co[t] = co;
    }

    // ---- A: f16 convert + swizzled transposed ds_write ----
    #pragma unroll
    for (int k = 0; k < 4; ++k) {
        const int i = t + (k << 9);
        const int c = i >> 3;
        const int r = (i >> 1) & 3;
        const int q = i & 1;
        const int chunk = c >> 3, cl = c & 7;
        const int pb = r * 8 + q * 4;
        const float vv[4] = {avf[k].x, avf[k].y, avf[k].z, avf[k].w};
        #pragma unroll
        for (int j = 0; j < 4; ++j) {
            const int p = pb + j;
            A16[p * 256 + (((chunk ^ (p & 7)) << 3) + cl)] =
                __half_as_ushort(__float2half(vv[j]));
        }
    }

    __syncthreads();   // warp meta + A ready

    if (contained) {
        // ---- pipelined fused B-stage: double-buffered 8-load slots ----
        uint4   v0[2][4], v1[2][4];    // [buf][corner], half 0 / half 1
        __half2 wb[2][4];
        int     ob[2];

        auto issueSlot = [&](int k, int buf) {
            const int idx = t + k * 512;
            ob[buf] = -1;
            if (idx < BITEMS) {
                const int r = idx >> 4, c = idx & 15;
                ob[buf] = r * 128 + ((c ^ (r & 7)) << 3);
                const float4 cw = s_cw[r];
                const int4   co = s_co[r];
                wb[buf][0] = __float2half2_rn(cw.x);
                wb[buf][1] = __float2half2_rn(cw.y);
                wb[buf][2] = __float2half2_rn(cw.z);
                wb[buf][3] = __float2half2_rn(cw.w);
                const ushort* base = f2u + c * 8;
                const ushort* p0 = base + (size_t)co.x * CCH;
                const ushort* p1 = base + (size_t)co.y * CCH;
                const ushort* p2 = base + (size_t)co.z * CCH;
                const ushort* p3 = base + (size_t)co.w * CCH;
                v0[buf][0] = *(const uint4*)p0;  v1[buf][0] = *(const uint4*)(p0 + 128);
                v0[buf][1] = *(const uint4*)p1;  v1[buf][1] = *(const uint4*)(p1 + 128);
                v0[buf][2] = *(const uint4*)p2;  v1[buf][2] = *(const uint4*)(p2 + 128);
                v0[buf][3] = *(const uint4*)p3;  v1[buf][3] = *(const uint4*)(p3 + 128);
            }
        };

        issueSlot(0, 0);
        #pragma unroll
        for (int k = 0; k < NSLOT; ++k) {
            const int cb = k & 1;
            if (k + 1 < NSLOT) issueSlot(k + 1, cb ^ 1);
            if (ob[cb] >= 0) {
                const __half2 w0 = wb[cb][0], w1 = wb[cb][1];
                const __half2 w2 = wb[cb][2], w3 = wb[cb][3];
                uint4 o0, o1;
                o0.x = h2fma4(v0[cb][0].x, v0[cb][1].x, v0[cb][2].x, v0[cb][3].x, w0, w1, w2, w3);
                o0.y = h2fma4(v0[cb][0].y, v0[cb][1].y, v0[cb][2].y, v0[cb][3].y, w0, w1, w2, w3);
                o0.z = h2fma4(v0[cb][0].z, v0[cb][1].z, v0[cb][2].z, v0[cb][3].z, w0, w1, w2, w3);
                o0.w = h2fma4(v0[cb][0].w, v0[cb][1].w, v0[cb][2].w, v0[cb][3].w, w0, w1, w2, w3);
                o1.x = h2fma4(v1[cb][0].x, v1[cb][1].x, v1[cb][2].x, v1[cb][3].x, w0, w1, w2, w3);
                o1.y = h2fma4(v1[cb][0].y, v1[cb][1].y, v1[cb][2].y, v1[cb][3].y, w0, w1, w2, w3);
                o1.z = h2fma4(v1[cb][0].z, v1[cb][1].z, v1[cb][2].z, v1[cb][3].z, w0, w1, w2, w3);
                o1.w = h2fma4(v1[cb][0].w, v1[cb][1].w, v1[cb][2].w, v1[cb][3].w, w0, w1, w2, w3);
                *(uint4*)(B0 + ob[cb]) = o0;
                *(uint4*)(B1 + ob[cb]) = o1;
            }
        }
        __syncthreads();   // A, B0, B1 all staged

        // ---- MFMA: both halves back-to-back ----
        const int mt = wv & 1;          // m-tile (16 px)
        const int ng = wv >> 1;         // n-group
        const int nnt = (ng == 3) ? 2 : 3;
        int nt[3] = {ng, ng + 4, ng + 8};
        f32x4 acc[3];
        #pragma unroll
        for (int i = 0; i < 3; ++i) acc[i] = f32x4{0.f, 0.f, 0.f, 0.f};

        const int g    = l >> 4;
        const int arow = mt * 16 + (l & 15);
        const int axr  = arow & 7;

        {
            f16x8 af[8];
            #pragma unroll
            for (int s = 0; s < 4; ++s) {
                af[s]     = ldfrag(A16 + arow * 256 + (((s * 4 + g) ^ axr) << 3));
                af[4 + s] = ldfrag(A16 + arow * 256 + (((16 + s * 4 + g) ^ axr) << 3));
            }
            #pragma unroll
            for (int i = 0; i < 3; ++i) if (i < nnt) {
                const int brow = nt[i] * 16 + (l & 15);
                const int bxr  = brow & 7;
                #pragma unroll
                for (int s = 0; s < 4; ++s) {
                    const f16x8 bf0 = ldfrag(B0 + brow * 128 + (((s * 4 + g) ^ bxr) << 3));
                    acc[i] = __builtin_amdgcn_mfma_f32_16x16x32_f16(af[s], bf0, acc[i], 0, 0, 0);
                    const f16x8 bf1 = ldfrag(B1 + brow * 128 + (((s * 4 + g) ^ bxr) << 3));
                    acc[i] = __builtin_amdgcn_mfma_f32_16x16x32_f16(af[4 + s], bf1, acc[i], 0, 0, 0);
                }
            }
        }
        __syncthreads();   // A,B dead -> D may overlay

        // ---- D -> LDS ----
        #pragma unroll
        for (int i = 0; i < 3; ++i) if (i < nnt) {
            #pragma unroll
            for (int r4 = 0; r4 < 4; ++r4) {
                Dex[(mt * 16 + (l >> 4) * 4 + r4) * DSTR + nt[i] * 16 + (l & 15)] = acc[i][r4];
            }
        }
        __syncthreads();

        // ---- output: bilinear combine of 4 D entries per (pixel, k) ----
        for (int idx = t; idx < 32 * KWIN; idx += 512) {
            const int p = idx & 31, k = idx >> 5;
            const int dyi = k / 7, dxi = k - dyi * 7;
            const int pos = (s_lby[p] + dyi) * UW + s_lbx[p] + dxi;
            const float* dr = Dex + p * DSTR + pos;
            const float d00 = dr[0], d01 = dr[1], d10 = dr[UW], d11 = dr[UW + 1];
            const float fx = s_fx[p], fy = s_fy[p];
            const float w00 = (1.f - fx) * (1.f - fy);
            const float w01 = fx * (1.f - fy);
            const float w10 = (1.f - fx) * fy;
            const float w11 = fx * fy;
            const float r = (w00 * d00 + w01 * d01 + w10 * d10 + w11 * d11) * 0.0625f;
            const int n = n0 + ((p >> 3) << 6) + (p & 7);
            outc[(size_t)(b * KWIN + k) * HW + n] = r;
        }
    } else {
        // ---- fallback: general coords, per-pixel gather, warp on the fly ----
        // (cold path: c0 is an identity grid on this data, containment holds)
        float* sDw = (float*)RAW + wv * 64;
        for (int p = wv; p < 32; p += 8) {
            const int n = n0 + ((p >> 3) << 6) + (p & 7);
            const float cx = c0[(b * 2 + 0) * HW + n];
            const float cy = c0[(b * 2 + 1) * HW + n];
            const float x0f = floorf(cx), y0f = floorf(cy);
            const float fx = cx - x0f, fy = cy - y0f;
            const int bx = (int)x0f - 3, by = (int)y0f - 3;
            const int ix = l & 7, iy = l >> 3;
            const int px = bx + ix, py = by + iy;
            float a = 0.f;
            if (px >= 0 && px < WDIM && py >= 0 && py < WDIM) {
                const int np = py * WDIM + px;
                const float wcx = c1[(b * 2 + 0) * HW + np];
                const float wcy = c1[(b * 2 + 1) * HW + np];
                const float wx0f = floorf(wcx), wy0f = floorf(wcy);
                const float gx = wcx - wx0f, gy = wcy - wy0f;
                const int jx0 = (int)wx0f, jy0 = (int)wy0f;
                const int jx1 = jx0 + 1,   jy1 = jy0 + 1;
                float w00 = (1.f - gx) * (1.f - gy);
                float w01 = gx * (1.f - gy);
                float w10 = (1.f - gx) * gy;
                float w11 = gx * gy;
                if (jx0 < 0 || jx0 >= WDIM) { w00 = 0.f; w10 = 0.f; }
                if (jx1 < 0 || jx1 >= WDIM) { w01 = 0.f; w11 = 0.f; }
                if (jy0 < 0 || jy0 >= WDIM) { w00 = 0.f; w01 = 0.f; }
                if (jy1 < 0 || jy1 >= WDIM) { w10 = 0.f; w11 = 0.f; }
                const int kx0 = min(max(jx0, 0), WDIM - 1);
                const int kx1 = min(max(jx1, 0), WDIM - 1);
                const int ky0 = min(max(jy0, 0), WDIM - 1);
                const int ky1 = min(max(jy1, 0), WDIM - 1);
                const ushort* e0 = f2u + (size_t)(ky0 * WDIM + kx0) * CCH;
                const ushort* e1 = f2u + (size_t)(ky0 * WDIM + kx1) * CCH;
                const ushort* e2 = f2u + (size_t)(ky1 * WDIM + kx0) * CCH;
                const ushort* e3 = f2u + (size_t)(ky1 * WDIM + kx1) * CCH;
                for (int c = 0; c < 32; ++c) {
                    float w8[8] = {0.f,0.f,0.f,0.f,0.f,0.f,0.f,0.f};
                    blend8(*(const uint4*)(e0 + c * 8), w00, w8);
                    blend8(*(const uint4*)(e1 + c * 8), w01, w8);
                    blend8(*(const uint4*)(e2 + c * 8), w10, w8);
                    blend8(*(const uint4*)(e3 + c * 8), w11, w8);
                    #pragma unroll
                    for (int e = 0; e < 8; ++e) {
                        const float q = __half2float(__float2half(
                            f1f[(size_t)(c * 8 + e) * HW + n]));
                        a += q * w8[e];
                    }
                }
            }
            sDw[l] = a;   // same-wave producer/consumer
            const int k = l;
            if (k < KWIN) {
                const int dyi = k / 7, dxi = k - dyi * 7;
                const int s = dyi * 8 + dxi;
                const float d00 = sDw[s], d01 = sDw[s + 1];
                const float d10 = sDw[s + 8], d11 = sDw[s + 9];
                const float w00 = (1.f - fx) * (1.f - fy);
                const float w01 = fx * (1.f - fy);
                const float w10 = (1.f - fx) * fy;
                const float w11 = fx * fy;
                const float r = (w00 * d00 + w01 * d01 + w10 * d10 + w11 * d11) * 0.0625f;
                outc[(size_t)(b * KWIN + k) * HW + n] = r;
            }
        }
    }
}

extern "C" void kernel_launch(void* const* d_in, const int* in_sizes, int n_in,
                              void* d_out, int out_size, void* d_ws, size_t ws_size,
                              hipStream_t stream) {
    (void)in_sizes; (void)n_in; (void)out_size; (void)ws_size;
    const float* f1 = (const float*)d_in[0];
    const float* f2 = (const float*)d_in[1];
    const float* c1 = (const float*)d_in[2];
    const float* c0 = (const float*)d_in[3];
    float* out = (float*)d_out;

    __half* f2t = (__half*)d_ws;           // [B,HW,C] f16, 4 MB

    dim3 g1(BATCH * (HW / 64), CCH / 32);
    transpose_kernel<<<g1, 256, 0, stream>>>(f2, c1, f2t, out);

    corr_fused_kernel<<<(BATCH * HW) / 32, 512, 0, stream>>>(
        f1, f2t, c1, c0, out + BATCH * 2 * HW);
}